// Round 24
// baseline (40.210 us; speedup 1.0000x reference)
//
#include <hip/hip_runtime.h>
#include <hip/hip_bf16.h>
#include <math.h>

#define DD 32
#define HH 128

typedef __attribute__((ext_vector_type(8))) __bf16 bf16x8;
typedef __attribute__((ext_vector_type(4))) float  f32x4;
typedef __attribute__((ext_vector_type(2))) int    i32x2;

// ---- ws layout (float offsets) -------------------------------------------
// [0,192)    tripg : 6 x 32 raw triple gradients
// [224,352)  c0    : vb1[kh] + t * vW1[32][kh]
// [384,16768) frags: 64 frags, lane-major (frag*64+lane)*4 floats
#define WS_TRIPG 0
#define WS_C0    224
#define WS_FRAG  384

union b8u { bf16x8 v; uint32_t u[4]; };

__device__ __forceinline__ f32x4 mfma16(bf16x8 a, bf16x8 b, f32x4 c) {
    return __builtin_amdgcn_mfma_f32_16x16x32_bf16(a, b, c, 0, 0, 0);
}

// ---- primitives (proven R14/R22/R23) --------------------------------------
__device__ __forceinline__ uint32_t cvtpk(float a, float b) {
    uint32_t r;
    asm("v_cvt_pk_bf16_f32 %0, %1, %2" : "=v"(r) : "v"(a), "v"(b));
    return r;
}
__device__ __forceinline__ float vexp2(float x) {   // 2^x
    float r; asm("v_exp_f32 %0, %1" : "=v"(r) : "v"(x)); return r;
}
__device__ __forceinline__ float vrcp(float x) {    // 1/x approx
    float r; asm("v_rcp_f32 %0, %1" : "=v"(r) : "v"(x)); return r;
}

#define TWO_LOG2E 2.8853900817779268f   // e^{2x} = 2^{x*TWO_LOG2E}

__device__ __forceinline__ float tanh_fast(float x) {   // 1 - 2/(e^{2x}+1)
    float e = vexp2(x * TWO_LOG2E);
    float q = 2.0f * vrcp(e + 1.0f);
    return 1.0f - q;
}
__device__ __forceinline__ float wsech2(float w, float x) { // w*q*(2-q)
    float e = vexp2(x * TWO_LOG2E);
    float q = 2.0f * vrcp(e + 1.0f);
    return w * (q * (2.0f - q));
}

// prep-only split (runs once)
__device__ __forceinline__ void split2(float a, float b,
                                       uint32_t& h, uint32_t& l) {
    __hip_bfloat162 hb = __float22bfloat162_rn(make_float2(a, b));
    uint32_t hu; __builtin_memcpy(&hu, &hb, 4);
    float af = __uint_as_float(hu << 16);
    float bf = __uint_as_float(hu & 0xffff0000u);
    __hip_bfloat162 lb = __float22bfloat162_rn(make_float2(a - af, b - bf));
    uint32_t lu; __builtin_memcpy(&lu, &lb, 4);
    h = hu; l = lu;
}

// ---- Prep: c0 + frag table (identical to R14/R22/R23) ---------------------
__global__ void k_prep(const float* __restrict__ t,
                       const float* __restrict__ vW1,  // (33,128)
                       const float* __restrict__ vb1,  // (128)
                       const float* __restrict__ vW2,  // (128,32)
                       const float* __restrict__ pW1,  // (32,128)
                       float* __restrict__ ws)
{
    int tid = blockIdx.x * 256 + threadIdx.x;
    if (tid < 4096) {
        int f = tid >> 6, lane = tid & 63;
        int g = lane >> 4, m = lane & 15;
        int reg  = f >> 5;          // 0:net1  1:net2
        int s    = (f >> 3) & 3;
        int slot = f & 7;
        bool isLo = slot & 1;
        float v[8];
        if (slot < 4) {             // A-operand (vW1 / pW1), th = 2s+(slot>>1)
            const float* W = reg ? pW1 : vW1;
            int th = 2 * s + (slot >> 1);
            #pragma unroll
            for (int i = 0; i < 8; i++)
                v[i] = W[(8 * g + i) * HH + 16 * th + m];
        } else {                    // B-operand, nt = (slot-4)>>1
            int nt = (slot - 4) >> 1;
            #pragma unroll
            for (int i = 0; i < 8; i++) {
                int kh = 16 * (2 * s + (i >> 2)) + 4 * g + (i & 3);
                v[i] = reg ? pW1[(nt * 16 + m) * HH + kh]
                           : vW2[kh * DD + nt * 16 + m];
            }
        }
        b8u H, L;
        #pragma unroll
        for (int j = 0; j < 4; j++)
            split2(v[2 * j], v[2 * j + 1], H.u[j], L.u[j]);
        *(f32x4*)(ws + WS_FRAG + (size_t)(f * 64 + lane) * 4) =
            isLo ? *(f32x4*)&L : *(f32x4*)&H;
    } else if (tid < 4096 + HH) {
        int k = tid - 4096;
        ws[WS_C0 + k] = vb1[k] + t[0] * vW1[DD * HH + k];
    }
}

// ---- decode work item p -> rows (a,b) and mode ----------------------------
// mode 0: pair (-G/+G); 1: zero-force pseudo-pair; 2: grad-extra; 3: oob.
__device__ __forceinline__ int decode(int p, int np, const int* perm,
                                      int& a, int& b) {
    if (p < np) {
        i32x2 pr = *(const i32x2*)(perm + 2 * p);
        a = pr[0]; b = pr[1];
        return 0;
    } else if (p == np) {
        a = perm[2 * np]; b = perm[2 * np + 1];
        return 1;
    } else if (p == np + 1) {
        a = perm[2 * np + 2]; b = a;
        return 1;
    } else if (p < np + 8) {
        int k = p - np - 2;
        int i3 = k >> 1, r3 = k & 1;
        int j3 = r3 + ((r3 >= i3) ? 1 : 0);
        a = perm[2 * np + i3]; b = perm[2 * np + j3];
        return 2;
    }
    a = 0; b = 0;
    return 3;
}

// ---- Main: pair-centric, 32 pairs per wave (two halves share frags) -------
// Per half: dzdt both rows + grad once per pair (R23 body). Halves share
// every frag/bias load -> half the L2 frag traffic, 2x MFMA chains.
__global__ __launch_bounds__(256) void k_main(
    const float* __restrict__ z,
    const float* __restrict__ ws,
    const int*   __restrict__ perm,
    const float* __restrict__ vb2,
    const float* __restrict__ pb1,
    const float* __restrict__ pW2,
    float* __restrict__ out,
    float* __restrict__ tripg,
    int np, int ntiles)
{
    int lane = threadIdx.x & 63;
    int tt   = blockIdx.x * 4 + (threadIdx.x >> 6);
    if (tt >= ntiles) return;
    int g = lane >> 4, m = lane & 15;

    int pbase = tt * 32;
    int a0, b0, a1, b1;
    decode(pbase + m,      np, perm, a0, b0);
    decode(pbase + 16 + m, np, perm, a1, b1);

    // issue all 8 row loads up front
    const float* pa0 = z + (size_t)a0 * DD + 8 * g;
    const float* pb0 = z + (size_t)b0 * DD + 8 * g;
    const float* pa1 = z + (size_t)a1 * DD + 8 * g;
    const float* pb1v = z + (size_t)b1 * DD + 8 * g;
    f32x4 xa0 = *(const f32x4*)pa0, xa1 = *(const f32x4*)(pa0 + 4);
    f32x4 xb0 = *(const f32x4*)pb0, xb1 = *(const f32x4*)(pb0 + 4);
    f32x4 ya0 = *(const f32x4*)pa1, ya1 = *(const f32x4*)(pa1 + 4);
    f32x4 yb0 = *(const f32x4*)pb1v, yb1 = *(const f32x4*)(pb1v + 4);
    float vb20 = vb2[m], vb21 = vb2[16 + m];

    // bf16 packs per half: ZA,ZB,D
    b8u ZA0, ZB0, D0, ZA1, ZB1, D1;
    ZA0.u[0] = cvtpk(xa0[0], xa0[1]); ZA0.u[1] = cvtpk(xa0[2], xa0[3]);
    ZA0.u[2] = cvtpk(xa1[0], xa1[1]); ZA0.u[3] = cvtpk(xa1[2], xa1[3]);
    ZB0.u[0] = cvtpk(xb0[0], xb0[1]); ZB0.u[1] = cvtpk(xb0[2], xb0[3]);
    ZB0.u[2] = cvtpk(xb1[0], xb1[1]); ZB0.u[3] = cvtpk(xb1[2], xb1[3]);
    D0.u[0]  = cvtpk(xa0[0] - xb0[0], xa0[1] - xb0[1]);
    D0.u[1]  = cvtpk(xa0[2] - xb0[2], xa0[3] - xb0[3]);
    D0.u[2]  = cvtpk(xa1[0] - xb1[0], xa1[1] - xb1[1]);
    D0.u[3]  = cvtpk(xa1[2] - xb1[2], xa1[3] - xb1[3]);
    ZA1.u[0] = cvtpk(ya0[0], ya0[1]); ZA1.u[1] = cvtpk(ya0[2], ya0[3]);
    ZA1.u[2] = cvtpk(ya1[0], ya1[1]); ZA1.u[3] = cvtpk(ya1[2], ya1[3]);
    ZB1.u[0] = cvtpk(yb0[0], yb0[1]); ZB1.u[1] = cvtpk(yb0[2], yb0[3]);
    ZB1.u[2] = cvtpk(yb1[0], yb1[1]); ZB1.u[3] = cvtpk(yb1[2], yb1[3]);
    D1.u[0]  = cvtpk(ya0[0] - yb0[0], ya0[1] - yb0[1]);
    D1.u[1]  = cvtpk(ya0[2] - yb0[2], ya0[3] - yb0[3]);
    D1.u[2]  = cvtpk(ya1[0] - yb1[0], ya1[1] - yb1[1]);
    D1.u[3]  = cvtpk(ya1[2] - yb1[2], ya1[3] - yb1[3]);

    // ---- net1: dzdt for 4 row sets (shared frag loads) ---------------------
    f32x4 vA00 = (f32x4){vb20, vb20, vb20, vb20};
    f32x4 vA01 = (f32x4){vb21, vb21, vb21, vb21};
    f32x4 vB00 = vA00, vB01 = vA01;
    f32x4 vA10 = vA00, vA11 = vA01;
    f32x4 vB10 = vA00, vB11 = vA01;
    {
        const float* fa = ws + WS_FRAG + (size_t)lane * 4;
        const float* fb = fa + 4 * 256;
        const float* cg = ws + WS_C0 + 4 * g;
        #pragma unroll 1
        for (int s = 0; s < 4; s++, fa += 8 * 256, fb += 8 * 256) {
            bf16x8 w1h0 = *(const bf16x8*)(fa + 0 * 256);
            bf16x8 w1h1 = *(const bf16x8*)(fa + 2 * 256);
            f32x4 c0v = *(const f32x4*)(cg + 32 * s);
            f32x4 c1v = *(const f32x4*)(cg + 32 * s + 16);
            f32x4 uA00 = c0v, uA01 = c1v, uB00 = c0v, uB01 = c1v;
            f32x4 uA10 = c0v, uA11 = c1v, uB10 = c0v, uB11 = c1v;
            uA00 = mfma16(w1h0, ZA0.v, uA00); uA01 = mfma16(w1h1, ZA0.v, uA01);
            uB00 = mfma16(w1h0, ZB0.v, uB00); uB01 = mfma16(w1h1, ZB0.v, uB01);
            uA10 = mfma16(w1h0, ZA1.v, uA10); uA11 = mfma16(w1h1, ZA1.v, uA11);
            uB10 = mfma16(w1h0, ZB1.v, uB10); uB11 = mfma16(w1h1, ZB1.v, uB11);
            b8u AA0, AB0, AA1, AB1;
            AA0.u[0] = cvtpk(tanh_fast(uA00[0]), tanh_fast(uA00[1]));
            AA0.u[1] = cvtpk(tanh_fast(uA00[2]), tanh_fast(uA00[3]));
            AA0.u[2] = cvtpk(tanh_fast(uA01[0]), tanh_fast(uA01[1]));
            AA0.u[3] = cvtpk(tanh_fast(uA01[2]), tanh_fast(uA01[3]));
            AB0.u[0] = cvtpk(tanh_fast(uB00[0]), tanh_fast(uB00[1]));
            AB0.u[1] = cvtpk(tanh_fast(uB00[2]), tanh_fast(uB00[3]));
            AB0.u[2] = cvtpk(tanh_fast(uB01[0]), tanh_fast(uB01[1]));
            AB0.u[3] = cvtpk(tanh_fast(uB01[2]), tanh_fast(uB01[3]));
            AA1.u[0] = cvtpk(tanh_fast(uA10[0]), tanh_fast(uA10[1]));
            AA1.u[1] = cvtpk(tanh_fast(uA10[2]), tanh_fast(uA10[3]));
            AA1.u[2] = cvtpk(tanh_fast(uA11[0]), tanh_fast(uA11[1]));
            AA1.u[3] = cvtpk(tanh_fast(uA11[2]), tanh_fast(uA11[3]));
            AB1.u[0] = cvtpk(tanh_fast(uB10[0]), tanh_fast(uB10[1]));
            AB1.u[1] = cvtpk(tanh_fast(uB10[2]), tanh_fast(uB10[3]));
            AB1.u[2] = cvtpk(tanh_fast(uB11[0]), tanh_fast(uB11[1]));
            AB1.u[3] = cvtpk(tanh_fast(uB11[2]), tanh_fast(uB11[3]));
            bf16x8 b0h = *(const bf16x8*)(fb + 0 * 256);
            bf16x8 b1h = *(const bf16x8*)(fb + 2 * 256);
            vA00 = mfma16(AA0.v, b0h, vA00); vA01 = mfma16(AA0.v, b1h, vA01);
            vB00 = mfma16(AB0.v, b0h, vB00); vB01 = mfma16(AB0.v, b1h, vB01);
            vA10 = mfma16(AA1.v, b0h, vA10); vA11 = mfma16(AA1.v, b1h, vA11);
            vB10 = mfma16(AB1.v, b0h, vB10); vB11 = mfma16(AB1.v, b1h, vB11);
        }
    }

    // ---- net2: grad once per pair, both halves -----------------------------
    f32x4 f00 = (f32x4){0.f, 0.f, 0.f, 0.f}, f01 = f00;
    f32x4 f10 = f00, f11 = f00;
    {
        const float* fa = ws + WS_FRAG + (size_t)(32 * 64 + lane) * 4;
        const float* fb = fa + 4 * 256;
        const float* bg = pb1 + 4 * g;
        const float* wg = pW2 + 4 * g;
        #pragma unroll 1
        for (int s = 0; s < 4; s++, fa += 8 * 256, fb += 8 * 256) {
            bf16x8 p1h0 = *(const bf16x8*)(fa + 0 * 256);
            bf16x8 p1h1 = *(const bf16x8*)(fa + 2 * 256);
            f32x4 c0v = *(const f32x4*)(bg + 32 * s);
            f32x4 c1v = *(const f32x4*)(bg + 32 * s + 16);
            f32x4 v00 = c0v, v01 = c1v, v10 = c0v, v11 = c1v;
            v00 = mfma16(p1h0, D0.v, v00); v01 = mfma16(p1h1, D0.v, v01);
            v10 = mfma16(p1h0, D1.v, v10); v11 = mfma16(p1h1, D1.v, v11);
            f32x4 w2q0 = *(const f32x4*)(wg + 32 * s);
            f32x4 w2q1 = *(const f32x4*)(wg + 32 * s + 16);
            b8u G0, G1;
            G0.u[0] = cvtpk(wsech2(w2q0[0], v00[0]), wsech2(w2q0[1], v00[1]));
            G0.u[1] = cvtpk(wsech2(w2q0[2], v00[2]), wsech2(w2q0[3], v00[3]));
            G0.u[2] = cvtpk(wsech2(w2q1[0], v01[0]), wsech2(w2q1[1], v01[1]));
            G0.u[3] = cvtpk(wsech2(w2q1[2], v01[2]), wsech2(w2q1[3], v01[3]));
            G1.u[0] = cvtpk(wsech2(w2q0[0], v10[0]), wsech2(w2q0[1], v10[1]));
            G1.u[1] = cvtpk(wsech2(w2q0[2], v10[2]), wsech2(w2q0[3], v10[3]));
            G1.u[2] = cvtpk(wsech2(w2q1[0], v11[0]), wsech2(w2q1[1], v11[1]));
            G1.u[3] = cvtpk(wsech2(w2q1[2], v11[2]), wsech2(w2q1[3], v11[3]));
            bf16x8 b0h = *(const bf16x8*)(fb + 0 * 256);
            bf16x8 b1h = *(const bf16x8*)(fb + 2 * 256);
            f00 = mfma16(G0.v, b0h, f00); f01 = mfma16(G0.v, b1h, f01);
            f10 = mfma16(G1.v, b0h, f10); f11 = mfma16(G1.v, b1h, f11);
        }
    }

    // ---- write both halves -------------------------------------------------
    #pragma unroll
    for (int r = 0; r < 4; r++) {
        {
            int p2 = pbase + 4 * g + r;
            int aw, bw;
            int mode = decode(p2, np, perm, aw, bw);
            if (mode == 0) {
                out[(size_t)aw * DD + m]      = vA00[r] - f00[r];
                out[(size_t)aw * DD + 16 + m] = vA01[r] - f01[r];
                out[(size_t)bw * DD + m]      = vB00[r] + f00[r];
                out[(size_t)bw * DD + 16 + m] = vB01[r] + f01[r];
            } else if (mode == 1) {
                out[(size_t)aw * DD + m]      = vA00[r];
                out[(size_t)aw * DD + 16 + m] = vA01[r];
                out[(size_t)bw * DD + m]      = vB00[r];
                out[(size_t)bw * DD + 16 + m] = vB01[r];
            } else if (mode == 2) {
                int k = p2 - np - 2;
                tripg[k * DD + m]      = f00[r];
                tripg[k * DD + 16 + m] = f01[r];
            }
        }
        {
            int p2 = pbase + 16 + 4 * g + r;
            int aw, bw;
            int mode = decode(p2, np, perm, aw, bw);
            if (mode == 0) {
                out[(size_t)aw * DD + m]      = vA10[r] - f10[r];
                out[(size_t)aw * DD + 16 + m] = vA11[r] - f11[r];
                out[(size_t)bw * DD + m]      = vB10[r] + f10[r];
                out[(size_t)bw * DD + 16 + m] = vB11[r] + f11[r];
            } else if (mode == 1) {
                out[(size_t)aw * DD + m]      = vA10[r];
                out[(size_t)aw * DD + 16 + m] = vA11[r];
                out[(size_t)bw * DD + m]      = vB10[r];
                out[(size_t)bw * DD + 16 + m] = vB11[r];
            } else if (mode == 2) {
                int k = p2 - np - 2;
                tripg[k * DD + m]      = f10[r];
                tripg[k * DD + 16 + m] = f11[r];
            }
        }
    }
}

// ---- Triple combine: out[t_i] -= 2*(G(2i) + G(2i+1)) ----------------------
__global__ void k_triple_combine(
    const int*   __restrict__ perm,
    const float* __restrict__ tripg,
    float* __restrict__ out,
    int np)
{
    int tid = threadIdx.x;
    if (tid >= 3 * DD) return;
    int i = tid >> 5, d = tid & (DD - 1);
    int row = perm[2 * np + i];
    float s = tripg[(2 * i) * DD + d] + tripg[(2 * i + 1) * DD + d];
    out[(size_t)row * DD + d] -= 2.0f * s;
}

extern "C" void kernel_launch(void* const* d_in, const int* in_sizes, int n_in,
                              void* d_out, int out_size, void* d_ws, size_t ws_size,
                              hipStream_t stream) {
    const float* t    = (const float*)d_in[0];
    const float* z    = (const float*)d_in[1];
    const int*   perm = (const int*)  d_in[2];
    const float* vW1  = (const float*)d_in[3];
    const float* vb1  = (const float*)d_in[4];
    const float* vW2  = (const float*)d_in[5];
    const float* vb2  = (const float*)d_in[6];
    const float* pW1  = (const float*)d_in[7];
    const float* pb1  = (const float*)d_in[8];
    const float* pW2  = (const float*)d_in[9];
    // d_in[10] = pb2: constant, vanishes under grad — unused.

    float* out = (float*)d_out;
    float* ws  = (float*)d_ws;

    int B = in_sizes[2];
    int np, ntr;
    if ((B & 1) == 0) { np = B / 2;       ntr = 0; }
    else              { np = (B - 3) / 2; ntr = 1; }

    // work items: np pairs + (triple: 2 ZF pseudo-pairs + 6 grad extras)
    int nwork  = np + (ntr ? 8 : 0);
    int ntiles = (nwork + 31) >> 5;          // 32 pairs per wave

    k_prep<<<17, 256, 0, stream>>>(t, vW1, vb1, vW2, pW1, ws);
    k_main<<<(ntiles + 3) / 4, 256, 0, stream>>>(z, ws, perm, vb2, pb1, pW2,
                                                 out, ws + WS_TRIPG,
                                                 np, ntiles);
    if (ntr) {
        k_triple_combine<<<1, 128, 0, stream>>>(perm, ws + WS_TRIPG, out, np);
    }
}

// Round 25
// 34.504 us; speedup vs baseline: 1.1654x; 1.1654x over previous
//
#include <hip/hip_runtime.h>
#include <hip/hip_bf16.h>
#include <math.h>

#define DD 32
#define HH 128

typedef __attribute__((ext_vector_type(8))) __bf16 bf16x8;
typedef __attribute__((ext_vector_type(4))) float  f32x4;
typedef __attribute__((ext_vector_type(2))) int    i32x2;

// ---- ws layout (float offsets) -------------------------------------------
// [0,192)    tripg : 6 x 32 raw triple gradients
// [224,352)  c0    : vb1[kh] + t * vW1[32][kh]
// [384,16768) frags: 64 frags, lane-major (frag*64+lane)*4 floats
#define WS_TRIPG 0
#define WS_C0    224
#define WS_FRAG  384

union b8u { bf16x8 v; uint32_t u[4]; };

__device__ __forceinline__ f32x4 mfma16(bf16x8 a, bf16x8 b, f32x4 c) {
    return __builtin_amdgcn_mfma_f32_16x16x32_bf16(a, b, c, 0, 0, 0);
}

// ---- primitives (R14/R22-proven) ------------------------------------------
__device__ __forceinline__ uint32_t cvtpk(float a, float b) {
    uint32_t r;
    asm("v_cvt_pk_bf16_f32 %0, %1, %2" : "=v"(r) : "v"(a), "v"(b));
    return r;
}
__device__ __forceinline__ float vexp2(float x) {   // 2^x
    float r; asm("v_exp_f32 %0, %1" : "=v"(r) : "v"(x)); return r;
}
__device__ __forceinline__ float vrcp(float x) {    // 1/x approx
    float r; asm("v_rcp_f32 %0, %1" : "=v"(r) : "v"(x)); return r;
}

#define TWO_LOG2E 2.8853900817779268f   // e^{2x} = 2^{x*TWO_LOG2E}

__device__ __forceinline__ float tanh_fast(float x) {   // 1 - 2/(e^{2x}+1)
    float e = vexp2(x * TWO_LOG2E);
    float q = 2.0f * vrcp(e + 1.0f);
    return 1.0f - q;
}
__device__ __forceinline__ float wsech2(float w, float x) { // w*q*(2-q)
    float e = vexp2(x * TWO_LOG2E);
    float q = 2.0f * vrcp(e + 1.0f);
    return w * (q * (2.0f - q));
}

// prep-only split (runs once)
__device__ __forceinline__ void split2(float a, float b,
                                       uint32_t& h, uint32_t& l) {
    __hip_bfloat162 hb = __float22bfloat162_rn(make_float2(a, b));
    uint32_t hu; __builtin_memcpy(&hu, &hb, 4);
    float af = __uint_as_float(hu << 16);
    float bf = __uint_as_float(hu & 0xffff0000u);
    __hip_bfloat162 lb = __float22bfloat162_rn(make_float2(a - af, b - bf));
    uint32_t lu; __builtin_memcpy(&lu, &lb, 4);
    h = hu; l = lu;
}

// ---- Prep: c0 + frag table (identical to R14/R22) -------------------------
// kappa conventions (A and B share kappa -> correct for any hw k-order):
//   GEMM1 (K=32):  kappa1(g,i) = 8g + i
//   GEMM2 (K=128, step s): kappa2(g,s,i) = 16*(2s + (i>>2)) + 4g + (i&3)
__global__ void k_prep(const float* __restrict__ t,
                       const float* __restrict__ vW1,  // (33,128)
                       const float* __restrict__ vb1,  // (128)
                       const float* __restrict__ vW2,  // (128,32)
                       const float* __restrict__ pW1,  // (32,128)
                       float* __restrict__ ws)
{
    int tid = blockIdx.x * 256 + threadIdx.x;
    if (tid < 4096) {
        int f = tid >> 6, lane = tid & 63;
        int g = lane >> 4, m = lane & 15;
        int reg  = f >> 5;          // 0:net1  1:net2
        int s    = (f >> 3) & 3;
        int slot = f & 7;
        bool isLo = slot & 1;
        float v[8];
        if (slot < 4) {             // A-operand (vW1 / pW1), th = 2s+(slot>>1)
            const float* W = reg ? pW1 : vW1;
            int th = 2 * s + (slot >> 1);
            #pragma unroll
            for (int i = 0; i < 8; i++)
                v[i] = W[(8 * g + i) * HH + 16 * th + m];
        } else {                    // B-operand, nt = (slot-4)>>1
            int nt = (slot - 4) >> 1;
            #pragma unroll
            for (int i = 0; i < 8; i++) {
                int kh = 16 * (2 * s + (i >> 2)) + 4 * g + (i & 3);
                v[i] = reg ? pW1[(nt * 16 + m) * HH + kh]
                           : vW2[kh * DD + nt * 16 + m];
            }
        }
        b8u H, L;
        #pragma unroll
        for (int j = 0; j < 4; j++)
            split2(v[2 * j], v[2 * j + 1], H.u[j], L.u[j]);
        *(f32x4*)(ws + WS_FRAG + (size_t)(f * 64 + lane) * 4) =
            isLo ? *(f32x4*)&L : *(f32x4*)&H;
    } else if (tid < 4096 + HH) {
        int k = tid - 4096;
        ws[WS_C0 + k] = vb1[k] + t[0] * vW1[DD * HH + k];
    }
}

// ---- decode work item p -> rows (a,b) and mode ----------------------------
// mode 0: normal pair (force -G/+G); 1: zero-force pseudo-pair (dzdt only);
// 2: grad-extra (write G to tripg); 3: out of range.
__device__ __forceinline__ int decode(int p, int np, const int* perm,
                                      int& a, int& b) {
    if (p < np) {
        i32x2 pr = *(const i32x2*)(perm + 2 * p);
        a = pr[0]; b = pr[1];
        return 0;
    } else if (p == np) {                 // triple rows t0,t1: dzdt only
        a = perm[2 * np]; b = perm[2 * np + 1];
        return 1;
    } else if (p == np + 1) {             // triple row t2 (both sides same)
        a = perm[2 * np + 2]; b = a;
        return 1;
    } else if (p < np + 8) {              // 6 ordered triple grads
        int k = p - np - 2;
        int i3 = k >> 1, r3 = k & 1;
        int j3 = r3 + ((r3 >= i3) ? 1 : 0);
        a = perm[2 * np + i3]; b = perm[2 * np + j3];
        return 2;
    }
    a = 0; b = 0;
    return 3;
}

// ---- Main: pair-centric fused dzdt + force --------------------------------
// Wave owns 16 pairs: dzdt for both rows (sets A,B), grad ONCE per pair
// (set D). out[a] = dzdt_a - G, out[b] = dzdt_b + G (rows disjoint: perm
// is a permutation). Bitwise-identical math to R22 per output element.
__global__ __launch_bounds__(256) void k_main(
    const float* __restrict__ z,
    const float* __restrict__ ws,
    const int*   __restrict__ perm,
    const float* __restrict__ vb2,
    const float* __restrict__ pb1,
    const float* __restrict__ pW2,
    float* __restrict__ out,
    float* __restrict__ tripg,
    int np, int ntiles)
{
    int lane = threadIdx.x & 63;
    int tt   = blockIdx.x * 4 + (threadIdx.x >> 6);
    if (tt >= ntiles) return;
    int g = lane >> 4, m = lane & 15;

    int pbase = tt * 16;
    int a, b;
    decode(pbase + m, np, perm, a, b);

    // load both rows of the pair (issued up front)
    const float* pa = z + (size_t)a * DD + 8 * g;
    const float* pb = z + (size_t)b * DD + 8 * g;
    f32x4 za0 = *(const f32x4*)pa, za1 = *(const f32x4*)(pa + 4);
    f32x4 zb0 = *(const f32x4*)pb, zb1 = *(const f32x4*)(pb + 4);
    float vb20 = vb2[m], vb21 = vb2[16 + m];

    // bf16 packs: ZA (a-rows), ZB (b-rows), D = a-b
    b8u ZA, ZB, DH;
    ZA.u[0] = cvtpk(za0[0], za0[1]); ZA.u[1] = cvtpk(za0[2], za0[3]);
    ZA.u[2] = cvtpk(za1[0], za1[1]); ZA.u[3] = cvtpk(za1[2], za1[3]);
    ZB.u[0] = cvtpk(zb0[0], zb0[1]); ZB.u[1] = cvtpk(zb0[2], zb0[3]);
    ZB.u[2] = cvtpk(zb1[0], zb1[1]); ZB.u[3] = cvtpk(zb1[2], zb1[3]);
    DH.u[0] = cvtpk(za0[0] - zb0[0], za0[1] - zb0[1]);
    DH.u[1] = cvtpk(za0[2] - zb0[2], za0[3] - zb0[3]);
    DH.u[2] = cvtpk(za1[0] - zb1[0], za1[1] - zb1[1]);
    DH.u[3] = cvtpk(za1[2] - zb1[2], za1[3] - zb1[3]);

    // ---- net1: dz_dt for sets A and B (shared frag loads) ------------------
    f32x4 avA0 = (f32x4){vb20, vb20, vb20, vb20};
    f32x4 avA1 = (f32x4){vb21, vb21, vb21, vb21};
    f32x4 avB0 = avA0, avB1 = avA1;
    {
        const float* fa = ws + WS_FRAG + (size_t)lane * 4;
        const float* fb = fa + 4 * 256;
        const float* cg = ws + WS_C0 + 4 * g;
        #pragma unroll 1
        for (int s = 0; s < 4; s++, fa += 8 * 256, fb += 8 * 256) {
            bf16x8 w1h0 = *(const bf16x8*)(fa + 0 * 256);
            bf16x8 w1h1 = *(const bf16x8*)(fa + 2 * 256);
            f32x4 c0v = *(const f32x4*)(cg + 32 * s);
            f32x4 c1v = *(const f32x4*)(cg + 32 * s + 16);
            f32x4 uA0 = c0v, uA1 = c1v, uB0 = c0v, uB1 = c1v;
            uA0 = mfma16(w1h0, ZA.v, uA0);
            uA1 = mfma16(w1h1, ZA.v, uA1);
            uB0 = mfma16(w1h0, ZB.v, uB0);
            uB1 = mfma16(w1h1, ZB.v, uB1);
            b8u AA, AB;
            AA.u[0] = cvtpk(tanh_fast(uA0[0]), tanh_fast(uA0[1]));
            AA.u[1] = cvtpk(tanh_fast(uA0[2]), tanh_fast(uA0[3]));
            AA.u[2] = cvtpk(tanh_fast(uA1[0]), tanh_fast(uA1[1]));
            AA.u[3] = cvtpk(tanh_fast(uA1[2]), tanh_fast(uA1[3]));
            AB.u[0] = cvtpk(tanh_fast(uB0[0]), tanh_fast(uB0[1]));
            AB.u[1] = cvtpk(tanh_fast(uB0[2]), tanh_fast(uB0[3]));
            AB.u[2] = cvtpk(tanh_fast(uB1[0]), tanh_fast(uB1[1]));
            AB.u[3] = cvtpk(tanh_fast(uB1[2]), tanh_fast(uB1[3]));
            bf16x8 b0h = *(const bf16x8*)(fb + 0 * 256);
            bf16x8 b1h = *(const bf16x8*)(fb + 2 * 256);
            avA0 = mfma16(AA.v, b0h, avA0);
            avA1 = mfma16(AA.v, b1h, avA1);
            avB0 = mfma16(AB.v, b0h, avB0);
            avB1 = mfma16(AB.v, b1h, avB1);
        }
    }

    // ---- net2: grad_phi on D (once per pair) -------------------------------
    f32x4 af0 = (f32x4){0.f, 0.f, 0.f, 0.f}, af1 = af0;
    {
        const float* fa = ws + WS_FRAG + (size_t)(32 * 64 + lane) * 4;
        const float* fb = fa + 4 * 256;
        const float* bg = pb1 + 4 * g;
        const float* wg = pW2 + 4 * g;
        #pragma unroll 1
        for (int s = 0; s < 4; s++, fa += 8 * 256, fb += 8 * 256) {
            bf16x8 p1h0 = *(const bf16x8*)(fa + 0 * 256);
            bf16x8 p1h1 = *(const bf16x8*)(fa + 2 * 256);
            f32x4 c0v = *(const f32x4*)(bg + 32 * s);
            f32x4 c1v = *(const f32x4*)(bg + 32 * s + 16);
            f32x4 v0 = c0v, v1 = c1v;
            v0 = mfma16(p1h0, DH.v, v0);
            v1 = mfma16(p1h1, DH.v, v1);
            f32x4 w2q0 = *(const f32x4*)(wg + 32 * s);
            f32x4 w2q1 = *(const f32x4*)(wg + 32 * s + 16);
            b8u GH;
            GH.u[0] = cvtpk(wsech2(w2q0[0], v0[0]), wsech2(w2q0[1], v0[1]));
            GH.u[1] = cvtpk(wsech2(w2q0[2], v0[2]), wsech2(w2q0[3], v0[3]));
            GH.u[2] = cvtpk(wsech2(w2q1[0], v1[0]), wsech2(w2q1[1], v1[1]));
            GH.u[3] = cvtpk(wsech2(w2q1[2], v1[2]), wsech2(w2q1[3], v1[3]));
            bf16x8 b0h = *(const bf16x8*)(fb + 0 * 256);
            bf16x8 b1h = *(const bf16x8*)(fb + 2 * 256);
            af0 = mfma16(GH.v, b0h, af0);
            af1 = mfma16(GH.v, b1h, af1);
        }
    }

    // ---- write: lane (g,m) holds pair p2=pbase+4g+r, cols m / 16+m ---------
    #pragma unroll
    for (int r = 0; r < 4; r++) {
        int p2 = pbase + 4 * g + r;
        int aw, bw;
        int mode = decode(p2, np, perm, aw, bw);
        if (mode == 0) {
            out[(size_t)aw * DD + m]      = avA0[r] - af0[r];
            out[(size_t)aw * DD + 16 + m] = avA1[r] - af1[r];
            out[(size_t)bw * DD + m]      = avB0[r] + af0[r];
            out[(size_t)bw * DD + 16 + m] = avB1[r] + af1[r];
        } else if (mode == 1) {
            out[(size_t)aw * DD + m]      = avA0[r];
            out[(size_t)aw * DD + 16 + m] = avA1[r];
            out[(size_t)bw * DD + m]      = avB0[r];
            out[(size_t)bw * DD + 16 + m] = avB1[r];
        } else if (mode == 2) {
            int k = p2 - np - 2;
            tripg[k * DD + m]      = af0[r];
            tripg[k * DD + 16 + m] = af1[r];
        }
    }
}

// ---- Triple combine: out[t_i] -= 2*(G(2i) + G(2i+1)) ----------------------
__global__ void k_triple_combine(
    const int*   __restrict__ perm,
    const float* __restrict__ tripg,
    float* __restrict__ out,
    int np)
{
    int tid = threadIdx.x;
    if (tid >= 3 * DD) return;
    int i = tid >> 5, d = tid & (DD - 1);
    int row = perm[2 * np + i];
    float s = tripg[(2 * i) * DD + d] + tripg[(2 * i + 1) * DD + d];
    out[(size_t)row * DD + d] -= 2.0f * s;
}

extern "C" void kernel_launch(void* const* d_in, const int* in_sizes, int n_in,
                              void* d_out, int out_size, void* d_ws, size_t ws_size,
                              hipStream_t stream) {
    const float* t    = (const float*)d_in[0];
    const float* z    = (const float*)d_in[1];
    const int*   perm = (const int*)  d_in[2];
    const float* vW1  = (const float*)d_in[3];
    const float* vb1  = (const float*)d_in[4];
    const float* vW2  = (const float*)d_in[5];
    const float* vb2  = (const float*)d_in[6];
    const float* pW1  = (const float*)d_in[7];
    const float* pb1  = (const float*)d_in[8];
    const float* pW2  = (const float*)d_in[9];
    // d_in[10] = pb2: constant, vanishes under grad — unused.

    float* out = (float*)d_out;
    float* ws  = (float*)d_ws;

    int B = in_sizes[2];
    int np, ntr;
    if ((B & 1) == 0) { np = B / 2;       ntr = 0; }
    else              { np = (B - 3) / 2; ntr = 1; }

    // work items: np pairs + (triple: 2 ZF pseudo-pairs + 6 grad extras)
    int nwork  = np + (ntr ? 8 : 0);
    int ntiles = (nwork + 15) >> 4;

    k_prep<<<17, 256, 0, stream>>>(t, vW1, vb1, vW2, pW1, ws);
    k_main<<<(ntiles + 3) / 4, 256, 0, stream>>>(z, ws, perm, vb2, pb1, pW2,
                                                 out, ws + WS_TRIPG,
                                                 np, ntiles);
    if (ntr) {
        k_triple_combine<<<1, 128, 0, stream>>>(perm, ws + WS_TRIPG, out, np);
    }
}